// Round 1
// baseline (883.697 us; speedup 1.0000x reference)
//
#include <hip/hip_runtime.h>

// ---------------------------------------------------------------------------
// WinBinVecFC: grouped-linear -> 3x (GEMM + BatchNorm) -> 3 small GEMMs
// B=8192, G=430, IN=25, OUT=4 ; dims 1720 ->1024 ->512 ->256 ->64 ->32 ->2
// All fp32 (no fp32 MFMA on CDNA4 -> vector-ALU GEMMs this round).
// BN batch stats computed via deterministic per-blockrow partials (no atomics)
// and folded into the NEXT GEMM's A-load as y = x*a + c.
// ---------------------------------------------------------------------------

__device__ __forceinline__ float4 ld4(const float* p) {
    return *reinterpret_cast<const float4*>(p);
}
__device__ __forceinline__ void st4(float* p, float4 v) {
    *reinterpret_cast<float4*>(p) = v;
}

// ---------------------------------------------------------------------------
// Kernel 0: H0[b][g*4+o] = sum_i X[b,g,i] * Wg[g,i,o] + bg[g,o]
// One thread per (b,g) pair; X staged coalesced through LDS.
// ---------------------------------------------------------------------------
__global__ __launch_bounds__(256) void k_grouped(
    const float* __restrict__ X, const float* __restrict__ Wg,
    const float* __restrict__ bg, float* __restrict__ H0)
{
    __shared__ float Xs[6400];                 // 256 pairs * 25 floats
    const int tid = threadIdx.x;
    const size_t base = (size_t)blockIdx.x * 6400;
    #pragma unroll
    for (int c = 0; c < 25; ++c)
        Xs[c * 256 + tid] = X[base + c * 256 + tid];   // coalesced
    __syncthreads();

    const int idx = blockIdx.x * 256 + tid;    // b*430+g  (exactly covers range)
    const int g = idx % 430;
    const float* __restrict__ w = Wg + g * 100;
    float4 acc = ld4(bg + g * 4);
    const float* x = &Xs[tid * 25];            // stride 25 vs 32 banks: conflict-free
    #pragma unroll
    for (int i = 0; i < 25; ++i) {
        const float xi = x[i];
        const float4 wv = ld4(w + i * 4);      // L2-resident (Wg = 172 KB)
        acc.x = fmaf(xi, wv.x, acc.x);
        acc.y = fmaf(xi, wv.y, acc.y);
        acc.z = fmaf(xi, wv.z, acc.z);
        acc.w = fmaf(xi, wv.w, acc.w);
    }
    st4(H0 + (size_t)idx * 4, acc);            // coalesced float4
}

// ---------------------------------------------------------------------------
// Tiled f32 GEMM  Y = act(A) @ B + bias  with fused column sum/sumsq partials.
// act(A) = A*affa + affc (per-K-column) when AFFINE (folds previous BN).
// BM=BN=128, BK=8, 256 threads, 8x8 per thread (split 4+4 to keep LDS reads
// 2-way max). Partials written per blockIdx.y row -> deterministic.
// ---------------------------------------------------------------------------
template<bool AFFINE>
__global__ __launch_bounds__(256) void k_gemm_bn(
    const float* __restrict__ A, const float* __restrict__ B,
    const float* __restrict__ bias,
    const float* __restrict__ affa, const float* __restrict__ affc,
    float* __restrict__ Y, float* __restrict__ partial,
    int M, int N, int K)
{
    __shared__ float smem[2112];               // As: [0,1056) = 8 x (128+4)
                                               // Bs: [1056,2112)
    const int tid = threadIdx.x;
    const int tx = tid & 15, ty = tid >> 4;
    const int m0 = blockIdx.y * 128, n0 = blockIdx.x * 128;

    const int arow = tid >> 1, akq = (tid & 1) * 4;   // A staging: row, k-offset
    const int bkr = tid >> 5, bnq = (tid & 31) * 4;   // B staging: k-row, col

    float acc[8][8];
    #pragma unroll
    for (int i = 0; i < 8; ++i)
        #pragma unroll
        for (int j = 0; j < 8; ++j) acc[i][j] = 0.f;

    const float* Aptr = A + (size_t)(m0 + arow) * K + akq;
    const float* Bptr = B + (size_t)bkr * N + n0 + bnq;

    for (int k0 = 0; k0 < K; k0 += 8) {
        // --- global loads (issued before sync: prefetch) ---
        float4 av = ld4(Aptr + k0);
        if (AFFINE) {
            const float4 aa = ld4(affa + k0 + akq);
            const float4 cc = ld4(affc + k0 + akq);
            av.x = fmaf(av.x, aa.x, cc.x);
            av.y = fmaf(av.y, aa.y, cc.y);
            av.z = fmaf(av.z, aa.z, cc.z);
            av.w = fmaf(av.w, aa.w, cc.w);
        }
        const float4 bv = ld4(Bptr + (size_t)k0 * N);
        __syncthreads();                       // previous compute done
        // A transposed into LDS: As[k][m]  (2-way write conflict = free)
        smem[(akq + 0) * 132 + arow] = av.x;
        smem[(akq + 1) * 132 + arow] = av.y;
        smem[(akq + 2) * 132 + arow] = av.z;
        smem[(akq + 3) * 132 + arow] = av.w;
        st4(&smem[1056 + bkr * 132 + bnq], bv);
        __syncthreads();
        // --- compute ---
        #pragma unroll
        for (int k = 0; k < 8; ++k) {
            const float4 a0 = ld4(&smem[k * 132 + ty * 4]);
            const float4 a1 = ld4(&smem[k * 132 + 64 + ty * 4]);
            const float4 b0 = ld4(&smem[1056 + k * 132 + tx * 4]);
            const float4 b1 = ld4(&smem[1056 + k * 132 + 64 + tx * 4]);
            const float avv[8] = {a0.x,a0.y,a0.z,a0.w,a1.x,a1.y,a1.z,a1.w};
            const float bvv[8] = {b0.x,b0.y,b0.z,b0.w,b1.x,b1.y,b1.z,b1.w};
            #pragma unroll
            for (int i = 0; i < 8; ++i)
                #pragma unroll
                for (int j = 0; j < 8; ++j)
                    acc[i][j] = fmaf(avv[i], bvv[j], acc[i][j]);
        }
    }

    // --- epilogue: bias, store Y, per-thread column sums ---
    const float4 bias0 = ld4(bias + n0 + tx * 4);
    const float4 bias1 = ld4(bias + n0 + 64 + tx * 4);
    const float bcol[8] = {bias0.x,bias0.y,bias0.z,bias0.w,
                           bias1.x,bias1.y,bias1.z,bias1.w};
    float csum[8], csq[8];
    #pragma unroll
    for (int j = 0; j < 8; ++j) { csum[j] = 0.f; csq[j] = 0.f; }

    #pragma unroll
    for (int ih = 0; ih < 2; ++ih)
        #pragma unroll
        for (int ii = 0; ii < 4; ++ii) {
            const int grow = m0 + ih * 64 + ty * 4 + ii;
            const int r = ih * 4 + ii;
            float4 v0, v1;
            v0.x = acc[r][0] + bcol[0]; v0.y = acc[r][1] + bcol[1];
            v0.z = acc[r][2] + bcol[2]; v0.w = acc[r][3] + bcol[3];
            v1.x = acc[r][4] + bcol[4]; v1.y = acc[r][5] + bcol[5];
            v1.z = acc[r][6] + bcol[6]; v1.w = acc[r][7] + bcol[7];
            st4(Y + (size_t)grow * N + n0 + tx * 4, v0);
            st4(Y + (size_t)grow * N + n0 + 64 + tx * 4, v1);
            csum[0] += v0.x; csq[0] += v0.x * v0.x;
            csum[1] += v0.y; csq[1] += v0.y * v0.y;
            csum[2] += v0.z; csq[2] += v0.z * v0.z;
            csum[3] += v0.w; csq[3] += v0.w * v0.w;
            csum[4] += v1.x; csq[4] += v1.x * v1.x;
            csum[5] += v1.y; csq[5] += v1.y * v1.y;
            csum[6] += v1.z; csq[6] += v1.z * v1.z;
            csum[7] += v1.w; csq[7] += v1.w * v1.w;
        }

    // --- deterministic block-level column reduction via LDS (reuse smem) ---
    __syncthreads();                           // all compute reads of smem done
    #pragma unroll
    for (int jh = 0; jh < 2; ++jh)
        #pragma unroll
        for (int jj = 0; jj < 4; ++jj)
            smem[ty * 128 + jh * 64 + tx * 4 + jj] = csum[jh * 4 + jj];
    __syncthreads();
    if (tid < 128) {
        float s = 0.f;
        #pragma unroll
        for (int t = 0; t < 16; ++t) s += smem[t * 128 + tid];
        partial[(size_t)blockIdx.y * (2 * N) + n0 + tid] = s;
    }
    __syncthreads();
    #pragma unroll
    for (int jh = 0; jh < 2; ++jh)
        #pragma unroll
        for (int jj = 0; jj < 4; ++jj)
            smem[ty * 128 + jh * 64 + tx * 4 + jj] = csq[jh * 4 + jj];
    __syncthreads();
    if (tid < 128) {
        float s = 0.f;
        #pragma unroll
        for (int t = 0; t < 16; ++t) s += smem[t * 128 + tid];
        partial[(size_t)blockIdx.y * (2 * N) + N + n0 + tid] = s;
    }
}

// ---------------------------------------------------------------------------
// Reduce per-blockrow partials -> BN affine  a = g*rsqrt(var+eps), c = be-m*a
// ---------------------------------------------------------------------------
__global__ __launch_bounds__(256) void k_bn_finalize(
    const float* __restrict__ partial,
    const float* __restrict__ gamma, const float* __restrict__ beta,
    float* __restrict__ affa, float* __restrict__ affc,
    int N, int Mtiles, float invB)
{
    const int c = blockIdx.x * 256 + threadIdx.x;
    if (c >= N) return;
    float S = 0.f, Q = 0.f;
    for (int t = 0; t < Mtiles; ++t) {
        S += partial[(size_t)t * 2 * N + c];
        Q += partial[(size_t)t * 2 * N + N + c];
    }
    const float mean = S * invB;
    const float var = fmaxf(Q * invB - mean * mean, 0.f);
    const float s = rsqrtf(var + 1e-5f);
    const float a = gamma[c] * s;
    affa[c] = a;
    affc[c] = beta[c] - mean * a;
}

// ---------------------------------------------------------------------------
// Tail: out = ((BN(Y5) @ W6 + b6) @ W7 + b7) @ W8 + b8   (256->64->32->2)
// 32 rows per block; weights read via L1/L2 (W6=64KB, shared by all blocks).
// ---------------------------------------------------------------------------
__global__ __launch_bounds__(256) void k_tail(
    const float* __restrict__ Y5,
    const float* __restrict__ a5, const float* __restrict__ c5,
    const float* __restrict__ W6, const float* __restrict__ b6,
    const float* __restrict__ W7, const float* __restrict__ b7,
    const float* __restrict__ W8, const float* __restrict__ b8,
    float* __restrict__ out)
{
    __shared__ float Xs[32][260];
    __shared__ float h6s[32][66];
    __shared__ float h7s[32][34];
    const int tid = threadIdx.x;
    const int row0 = blockIdx.x * 32;

    // phase A: load 32x256 tile with BN affine applied
    #pragma unroll
    for (int c = 0; c < 8; ++c) {
        const int id = c * 256 + tid;          // float4 id
        const int r = id >> 6;
        const int k = (id & 63) * 4;
        float4 v = ld4(Y5 + (size_t)(row0 + r) * 256 + k);
        const float4 aa = ld4(a5 + k);
        const float4 cc = ld4(c5 + k);
        v.x = fmaf(v.x, aa.x, cc.x);
        v.y = fmaf(v.y, aa.y, cc.y);
        v.z = fmaf(v.z, aa.z, cc.z);
        v.w = fmaf(v.w, aa.w, cc.w);
        st4(&Xs[r][k], v);
    }
    __syncthreads();

    // phase B: h6[32][64], thread = (o = tid&63, row-group = tid>>6)
    {
        const int o = tid & 63;
        const int rg = tid >> 6;
        const float bb = b6[o];
        float acc[8];
        #pragma unroll
        for (int i = 0; i < 8; ++i) acc[i] = bb;
        for (int k = 0; k < 256; ++k) {
            const float w = W6[k * 64 + o];    // coalesced, cache-hot
            #pragma unroll
            for (int i = 0; i < 8; ++i)
                acc[i] = fmaf(Xs[rg * 8 + i][k], w, acc[i]);  // LDS broadcast
        }
        #pragma unroll
        for (int i = 0; i < 8; ++i) h6s[rg * 8 + i][o] = acc[i];
    }
    __syncthreads();

    // phase C: h7[32][32]
    {
        const int o = tid & 31;
        const int rg = tid >> 5;
        const float bb = b7[o];
        float acc[4];
        #pragma unroll
        for (int i = 0; i < 4; ++i) acc[i] = bb;
        for (int k = 0; k < 64; ++k) {
            const float w = W7[k * 32 + o];
            #pragma unroll
            for (int i = 0; i < 4; ++i)
                acc[i] = fmaf(h6s[rg * 4 + i][k], w, acc[i]);
        }
        #pragma unroll
        for (int i = 0; i < 4; ++i) h7s[rg * 4 + i][o] = acc[i];
    }
    __syncthreads();

    // phase D: out[32][2]
    if (tid < 64) {
        const int r = tid >> 1, o = tid & 1;
        float acc = b8[o];
        #pragma unroll
        for (int k = 0; k < 32; ++k)
            acc = fmaf(h7s[r][k], W8[k * 2 + o], acc);
        out[(size_t)(row0 + r) * 2 + o] = acc;
    }
}

// ---------------------------------------------------------------------------
extern "C" void kernel_launch(void* const* d_in, const int* in_sizes, int n_in,
                              void* d_out, int out_size, void* d_ws, size_t ws_size,
                              hipStream_t stream)
{
    const float* X   = (const float*)d_in[0];
    const float* Wg  = (const float*)d_in[1];
    const float* bg  = (const float*)d_in[2];
    const float* W3  = (const float*)d_in[3];
    const float* b3  = (const float*)d_in[4];
    const float* g3  = (const float*)d_in[5];
    const float* be3 = (const float*)d_in[6];
    const float* W4  = (const float*)d_in[7];
    const float* b4  = (const float*)d_in[8];
    const float* g4  = (const float*)d_in[9];
    const float* be4 = (const float*)d_in[10];
    const float* W5  = (const float*)d_in[11];
    const float* b5  = (const float*)d_in[12];
    const float* g5  = (const float*)d_in[13];
    const float* be5 = (const float*)d_in[14];
    const float* W6  = (const float*)d_in[15];
    const float* b6  = (const float*)d_in[16];
    const float* W7  = (const float*)d_in[17];
    const float* b7  = (const float*)d_in[18];
    const float* W8  = (const float*)d_in[19];
    const float* b8  = (const float*)d_in[20];
    float* out = (float*)d_out;

    // workspace layout (floats):
    //   H0  [8192*1720]   grouped output; later reused as Y4
    //   Y3  [8192*1024]   ; later reused as Y5
    //   partial [64*2*1024]
    //   affine  a3,c3,a4,c4,a5,c5
    float* ws = (float*)d_ws;
    float* H0 = ws;
    float* Y3 = ws + 14090240;                 // 8192*1720
    float* partial = Y3 + 8388608;             // 8192*1024
    float* a3 = partial + 131072;
    float* c3 = a3 + 1024;
    float* a4 = c3 + 1024;
    float* c4 = a4 + 512;
    float* a5 = c4 + 512;
    float* c5 = a5 + 256;
    float* Y4 = H0;                            // H0 dead after GEMM3
    float* Y5 = Y3;                            // Y3 dead after GEMM4

    const float invB = 1.f / 8192.f;

    k_grouped<<<13760, 256, 0, stream>>>(X, Wg, bg, H0);

    k_gemm_bn<false><<<dim3(8, 64), 256, 0, stream>>>(
        H0, W3, b3, nullptr, nullptr, Y3, partial, 8192, 1024, 1720);
    k_bn_finalize<<<4, 256, 0, stream>>>(partial, g3, be3, a3, c3, 1024, 64, invB);

    k_gemm_bn<true><<<dim3(4, 64), 256, 0, stream>>>(
        Y3, W4, b4, a3, c3, Y4, partial, 8192, 512, 1024);
    k_bn_finalize<<<2, 256, 0, stream>>>(partial, g4, be4, a4, c4, 512, 64, invB);

    k_gemm_bn<true><<<dim3(2, 64), 256, 0, stream>>>(
        Y4, W5, b5, a4, c4, Y5, partial, 8192, 256, 512);
    k_bn_finalize<<<1, 256, 0, stream>>>(partial, g5, be5, a5, c5, 256, 64, invB);

    k_tail<<<256, 256, 0, stream>>>(Y5, a5, c5, W6, b6, W7, b7, W8, b8, out);
}

// Round 2
// 395.228 us; speedup vs baseline: 2.2359x; 2.2359x over previous
//
#include <hip/hip_runtime.h>

// ---------------------------------------------------------------------------
// WinBinVecFC round 2: bf16 MFMA for the 3 mid GEMMs.
// grouped(bf16 out) -> GEMM3/4/5 via mfma_f32_16x16x32_bf16 (fp32 accum,
// fp32 BN stats, BN affine folded into next GEMM's staging) -> f32 tail.
// Weights transposed+cast to bf16 [N][Kpad] once per call (K3: 1720->1728 pad).
// ---------------------------------------------------------------------------

typedef __attribute__((ext_vector_type(8))) short bfrag;    // 8 bf16 (4 VGPR)
typedef __attribute__((ext_vector_type(4))) float f32x4v;   // MFMA C/D

__device__ __forceinline__ float4 ld4(const float* p) {
    return *reinterpret_cast<const float4*>(p);
}
__device__ __forceinline__ void st4(float* p, float4 v) {
    *reinterpret_cast<float4*>(p) = v;
}
// RNE f32 -> bf16 (deterministic, no header dependence)
__device__ __forceinline__ unsigned short f2b(float f) {
    union { float f; unsigned u; } v; v.f = f;
    unsigned r = v.u + 0x7fffu + ((v.u >> 16) & 1u);
    return (unsigned short)(r >> 16);
}

// ---------------------------------------------------------------------------
// Kernel 0: H0[b][g*4+o] = bf16( sum_i X[b,g,i]*Wg[g,i,o] + bg[g,o] )
// ---------------------------------------------------------------------------
__global__ __launch_bounds__(256) void k_grouped(
    const float* __restrict__ X, const float* __restrict__ Wg,
    const float* __restrict__ bg, unsigned short* __restrict__ H0)
{
    __shared__ float Xs[6400];                 // 256 pairs * 25 floats
    const int tid = threadIdx.x;
    const size_t base = (size_t)blockIdx.x * 6400;
    #pragma unroll
    for (int c = 0; c < 25; ++c)
        Xs[c * 256 + tid] = X[base + c * 256 + tid];   // coalesced
    __syncthreads();

    const int idx = blockIdx.x * 256 + tid;    // b*430+g (exact cover)
    const int g = idx % 430;
    const float* __restrict__ w = Wg + g * 100;
    float4 acc = ld4(bg + g * 4);
    const float* x = &Xs[tid * 25];
    #pragma unroll
    for (int i = 0; i < 25; ++i) {
        const float xi = x[i];
        const float4 wv = ld4(w + i * 4);      // L2-resident (172 KB)
        acc.x = fmaf(xi, wv.x, acc.x);
        acc.y = fmaf(xi, wv.y, acc.y);
        acc.z = fmaf(xi, wv.z, acc.z);
        acc.w = fmaf(xi, wv.w, acc.w);
    }
    ushort4 o;
    o.x = f2b(acc.x); o.y = f2b(acc.y); o.z = f2b(acc.z); o.w = f2b(acc.w);
    *reinterpret_cast<ushort4*>(H0 + (size_t)idx * 4) = o;   // 8B coalesced
}

// ---------------------------------------------------------------------------
// Weight prep: Wt[n][k] = bf16(W[k][n]), zero-pad k in [K, Kpad).
// block (32,8), tile 32x32 via LDS.
// ---------------------------------------------------------------------------
__global__ __launch_bounds__(256) void k_transpose_w(
    const float* __restrict__ W, unsigned short* __restrict__ Wt,
    int K, int N, int Kpad)
{
    __shared__ float t[32][33];
    const int tx = threadIdx.x, ty = threadIdx.y;
    const int k0 = blockIdx.y * 32, n0 = blockIdx.x * 32;
    #pragma unroll
    for (int r = 0; r < 4; ++r) {
        const int k = k0 + ty + r * 8;
        t[ty + r * 8][tx] = (k < K) ? W[(size_t)k * N + n0 + tx] : 0.f;
    }
    __syncthreads();
    #pragma unroll
    for (int r = 0; r < 4; ++r) {
        const int n = n0 + ty + r * 8;
        Wt[(size_t)n * Kpad + k0 + tx] = f2b(t[tx][ty + r * 8]);
    }
}

// ---------------------------------------------------------------------------
// MFMA GEMM: Y = act(A) @ Bt^T + bias, fused column sum/sumsq partials.
// AFFINE=false: A is bf16 [M][K].  AFFINE=true: A is f32 [M][K], y=x*a+c
// applied in fp32 during staging, then cast to bf16.
// Bt is bf16 [N][Kpad] (pre-transposed weights, K-pad zeroed).
// BM=BN=128, BK=64; 256 thr = 4 waves (2x2), wave tile 64x64 = 4x4 frags.
// LDS rows padded to 72 bf16 (144 B) -> <=2-way bank aliasing on b128 reads.
// ---------------------------------------------------------------------------
template<bool AFFINE>
__global__ __launch_bounds__(256) void k_gemm_mfma(
    const void* __restrict__ Asrc,
    const unsigned short* __restrict__ Bt,
    const float* __restrict__ bias,
    const float* __restrict__ affa, const float* __restrict__ affc,
    float* __restrict__ Y, float* __restrict__ partial,
    int M, int N, int K, int Kpad)
{
    constexpr int LDT = 72;
    __shared__ unsigned short As[128 * LDT];   // 18.4 KB
    __shared__ unsigned short Bs[128 * LDT];   // 18.4 KB

    const int tid = threadIdx.x;
    const int m0 = blockIdx.y * 128, n0 = blockIdx.x * 128;
    const int lane = tid & 63, wid = tid >> 6;
    const int wm = wid >> 1, wn = wid & 1;     // 2x2 wave grid
    const int lr = lane & 15, hi = lane >> 4;

    f32x4v acc[4][4] = {};

    // staging register buffers (only one A-path used per instantiation)
    bfrag ra[4]; ushort4 ru[8]; bfrag rb[4];

    const int ar8 = tid >> 3, ak8 = (tid & 7) * 8;     // bf16-A / B pattern
    const int arf = tid >> 4, akq = (tid & 15) * 4;    // f32-A pattern

    auto stage_load = [&](int kk) {
        if constexpr (!AFFINE) {
            const unsigned short* A = (const unsigned short*)Asrc;
            #pragma unroll
            for (int i = 0; i < 4; ++i) {
                bfrag v = {};
                if (kk + ak8 < K)
                    v = *reinterpret_cast<const bfrag*>(
                        A + (size_t)(m0 + ar8 + i * 32) * K + kk + ak8);
                ra[i] = v;
            }
        } else {
            const float* A = (const float*)Asrc;
            #pragma unroll
            for (int i = 0; i < 8; ++i) {
                float4 v = {0.f, 0.f, 0.f, 0.f};
                if (kk + akq < K) {
                    v = ld4(A + (size_t)(m0 + arf + i * 16) * K + kk + akq);
                    const float4 aa = ld4(affa + kk + akq);
                    const float4 cc = ld4(affc + kk + akq);
                    v.x = fmaf(v.x, aa.x, cc.x);
                    v.y = fmaf(v.y, aa.y, cc.y);
                    v.z = fmaf(v.z, aa.z, cc.z);
                    v.w = fmaf(v.w, aa.w, cc.w);
                }
                ushort4 u;
                u.x = f2b(v.x); u.y = f2b(v.y); u.z = f2b(v.z); u.w = f2b(v.w);
                ru[i] = u;
            }
        }
        #pragma unroll
        for (int i = 0; i < 4; ++i)
            rb[i] = *reinterpret_cast<const bfrag*>(
                Bt + (size_t)(n0 + ar8 + i * 32) * Kpad + kk + ak8);
    };

    const int Ksteps = (K + 63) >> 6;
    stage_load(0);

    for (int s = 0; s < Ksteps; ++s) {
        __syncthreads();                       // prev compute done
        if constexpr (!AFFINE) {
            #pragma unroll
            for (int i = 0; i < 4; ++i)
                *reinterpret_cast<bfrag*>(&As[(ar8 + i * 32) * LDT + ak8]) = ra[i];
        } else {
            #pragma unroll
            for (int i = 0; i < 8; ++i)
                *reinterpret_cast<ushort4*>(&As[(arf + i * 16) * LDT + akq]) = ru[i];
        }
        #pragma unroll
        for (int i = 0; i < 4; ++i)
            *reinterpret_cast<bfrag*>(&Bs[(ar8 + i * 32) * LDT + ak8]) = rb[i];
        __syncthreads();
        if (s + 1 < Ksteps) stage_load((s + 1) * 64);   // overlap w/ compute

        #pragma unroll
        for (int kc = 0; kc < 64; kc += 32) {
            bfrag af[4], bfv[4];
            #pragma unroll
            for (int mt = 0; mt < 4; ++mt)
                af[mt] = *reinterpret_cast<const bfrag*>(
                    &As[(wm * 64 + mt * 16 + lr) * LDT + kc + hi * 8]);
            #pragma unroll
            for (int nt = 0; nt < 4; ++nt)
                bfv[nt] = *reinterpret_cast<const bfrag*>(
                    &Bs[(wn * 64 + nt * 16 + lr) * LDT + kc + hi * 8]);
            #pragma unroll
            for (int mt = 0; mt < 4; ++mt)
                #pragma unroll
                for (int nt = 0; nt < 4; ++nt)
                    acc[mt][nt] = __builtin_amdgcn_mfma_f32_16x16x32_bf16(
                        af[mt], bfv[nt], acc[mt][nt], 0, 0, 0);
        }
    }

    // --- epilogue: bias, store f32 Y, column sum/sumsq ---
    float bcol[4];
    #pragma unroll
    for (int nt = 0; nt < 4; ++nt)
        bcol[nt] = bias[n0 + wn * 64 + nt * 16 + lr];

    float csum[4] = {0.f, 0.f, 0.f, 0.f}, csq[4] = {0.f, 0.f, 0.f, 0.f};
    #pragma unroll
    for (int mt = 0; mt < 4; ++mt)
        #pragma unroll
        for (int e = 0; e < 4; ++e) {
            const int m = m0 + wm * 64 + mt * 16 + hi * 4 + e;
            #pragma unroll
            for (int nt = 0; nt < 4; ++nt) {
                const float v = acc[mt][nt][e] + bcol[nt];
                Y[(size_t)m * N + n0 + wn * 64 + nt * 16 + lr] = v;
                csum[nt] += v; csq[nt] += v * v;
            }
        }

    // deterministic block reduction via LDS (reuse tiles)
    __syncthreads();
    float* redS = (float*)As;                  // 8 slots x 128 cols
    float* redQ = (float*)Bs;
    const int slot = wm * 4 + hi;
    #pragma unroll
    for (int nt = 0; nt < 4; ++nt) {
        const int c = wn * 64 + nt * 16 + lr;
        redS[slot * 128 + c] = csum[nt];
        redQ[slot * 128 + c] = csq[nt];
    }
    __syncthreads();
    if (tid < 128) {
        float s = 0.f, q = 0.f;
        #pragma unroll
        for (int t = 0; t < 8; ++t) {
            s += redS[t * 128 + tid];
            q += redQ[t * 128 + tid];
        }
        partial[(size_t)blockIdx.y * (2 * N) + n0 + tid] = s;
        partial[(size_t)blockIdx.y * (2 * N) + N + n0 + tid] = q;
    }
}

// ---------------------------------------------------------------------------
// BN finalize: a = gamma*rsqrt(var+eps), c = beta - mean*a
// ---------------------------------------------------------------------------
__global__ __launch_bounds__(256) void k_bn_finalize(
    const float* __restrict__ partial,
    const float* __restrict__ gamma, const float* __restrict__ beta,
    float* __restrict__ affa, float* __restrict__ affc,
    int N, int Mtiles, float invB)
{
    const int c = blockIdx.x * 256 + threadIdx.x;
    if (c >= N) return;
    float S = 0.f, Q = 0.f;
    for (int t = 0; t < Mtiles; ++t) {
        S += partial[(size_t)t * 2 * N + c];
        Q += partial[(size_t)t * 2 * N + N + c];
    }
    const float mean = S * invB;
    const float var = fmaxf(Q * invB - mean * mean, 0.f);
    const float s = rsqrtf(var + 1e-5f);
    const float a = gamma[c] * s;
    affa[c] = a;
    affc[c] = beta[c] - mean * a;
}

// ---------------------------------------------------------------------------
// Tail: out = ((BN(Y5) @ W6 + b6) @ W7 + b7) @ W8 + b8   (256->64->32->2)
// ---------------------------------------------------------------------------
__global__ __launch_bounds__(256) void k_tail(
    const float* __restrict__ Y5,
    const float* __restrict__ a5, const float* __restrict__ c5,
    const float* __restrict__ W6, const float* __restrict__ b6,
    const float* __restrict__ W7, const float* __restrict__ b7,
    const float* __restrict__ W8, const float* __restrict__ b8,
    float* __restrict__ out)
{
    __shared__ float Xs[32][260];
    __shared__ float h6s[32][66];
    __shared__ float h7s[32][34];
    const int tid = threadIdx.x;
    const int row0 = blockIdx.x * 32;

    #pragma unroll
    for (int c = 0; c < 8; ++c) {
        const int id = c * 256 + tid;
        const int r = id >> 6;
        const int k = (id & 63) * 4;
        float4 v = ld4(Y5 + (size_t)(row0 + r) * 256 + k);
        const float4 aa = ld4(a5 + k);
        const float4 cc = ld4(c5 + k);
        v.x = fmaf(v.x, aa.x, cc.x);
        v.y = fmaf(v.y, aa.y, cc.y);
        v.z = fmaf(v.z, aa.z, cc.z);
        v.w = fmaf(v.w, aa.w, cc.w);
        st4(&Xs[r][k], v);
    }
    __syncthreads();

    {
        const int o = tid & 63;
        const int rg = tid >> 6;
        const float bb = b6[o];
        float acc[8];
        #pragma unroll
        for (int i = 0; i < 8; ++i) acc[i] = bb;
        for (int k = 0; k < 256; ++k) {
            const float w = W6[k * 64 + o];
            #pragma unroll
            for (int i = 0; i < 8; ++i)
                acc[i] = fmaf(Xs[rg * 8 + i][k], w, acc[i]);
        }
        #pragma unroll
        for (int i = 0; i < 8; ++i) h6s[rg * 8 + i][o] = acc[i];
    }
    __syncthreads();

    {
        const int o = tid & 31;
        const int rg = tid >> 5;
        const float bb = b7[o];
        float acc[4];
        #pragma unroll
        for (int i = 0; i < 4; ++i) acc[i] = bb;
        for (int k = 0; k < 64; ++k) {
            const float w = W7[k * 32 + o];
            #pragma unroll
            for (int i = 0; i < 4; ++i)
                acc[i] = fmaf(h6s[rg * 4 + i][k], w, acc[i]);
        }
        #pragma unroll
        for (int i = 0; i < 4; ++i) h7s[rg * 4 + i][o] = acc[i];
    }
    __syncthreads();

    if (tid < 64) {
        const int r = tid >> 1, o = tid & 1;
        float acc = b8[o];
        #pragma unroll
        for (int k = 0; k < 32; ++k)
            acc = fmaf(h7s[r][k], W8[k * 2 + o], acc);
        out[(size_t)(row0 + r) * 2 + o] = acc;
    }
}

// ---------------------------------------------------------------------------
extern "C" void kernel_launch(void* const* d_in, const int* in_sizes, int n_in,
                              void* d_out, int out_size, void* d_ws, size_t ws_size,
                              hipStream_t stream)
{
    const float* X   = (const float*)d_in[0];
    const float* Wg  = (const float*)d_in[1];
    const float* bg  = (const float*)d_in[2];
    const float* W3  = (const float*)d_in[3];
    const float* b3  = (const float*)d_in[4];
    const float* g3  = (const float*)d_in[5];
    const float* be3 = (const float*)d_in[6];
    const float* W4  = (const float*)d_in[7];
    const float* b4  = (const float*)d_in[8];
    const float* g4  = (const float*)d_in[9];
    const float* be4 = (const float*)d_in[10];
    const float* W5  = (const float*)d_in[11];
    const float* b5  = (const float*)d_in[12];
    const float* g5  = (const float*)d_in[13];
    const float* be5 = (const float*)d_in[14];
    const float* W6  = (const float*)d_in[15];
    const float* b6  = (const float*)d_in[16];
    const float* W7  = (const float*)d_in[17];
    const float* b7  = (const float*)d_in[18];
    const float* W8  = (const float*)d_in[19];
    const float* b8  = (const float*)d_in[20];
    float* out = (float*)d_out;

    // workspace layout (bytes):
    //   [0)            H0 bf16 [8192][1720]   (28,180,480) ; reused as Y4 f32
    //   [28,180,480)   Y3 f32 [8192][1024]    (33,554,432) ; reused as Y5
    //   [61,734,912)   Wt3 bf16 [1024][1728]  ( 3,538,944)
    //   [65,273,856)   Wt4 bf16 [512][1024]   ( 1,048,576)
    //   [66,322,432)   Wt5 bf16 [256][512]    (   262,144)
    //   [66,584,576)   partial f32 [64][2*1024] (524,288)
    //   [67,108,864)   affines a3,c3,a4,c4,a5,c5
    char* wsb = (char*)d_ws;
    unsigned short* H0b = (unsigned short*)wsb;
    float* Y4           = (float*)wsb;                       // after H0 dead
    float* Y3           = (float*)(wsb + 28180480);
    float* Y5           = Y3;                                // after Y3 dead
    unsigned short* Wt3 = (unsigned short*)(wsb + 61734912);
    unsigned short* Wt4 = (unsigned short*)(wsb + 65273856);
    unsigned short* Wt5 = (unsigned short*)(wsb + 66322432);
    float* partial      = (float*)(wsb + 66584576);
    float* a3 = (float*)(wsb + 67108864);
    float* c3 = a3 + 1024;
    float* a4 = c3 + 1024;
    float* c4 = a4 + 512;
    float* a5 = c4 + 512;
    float* c5 = a5 + 256;

    const float invB = 1.f / 8192.f;

    // weight prep (tiny) + grouped layer
    k_transpose_w<<<dim3(32, 54), dim3(32, 8), 0, stream>>>(W3, Wt3, 1720, 1024, 1728);
    k_transpose_w<<<dim3(16, 32), dim3(32, 8), 0, stream>>>(W4, Wt4, 1024, 512, 1024);
    k_transpose_w<<<dim3( 8, 16), dim3(32, 8), 0, stream>>>(W5, Wt5,  512, 256,  512);
    k_grouped<<<13760, 256, 0, stream>>>(X, Wg, bg, H0b);

    k_gemm_mfma<false><<<dim3(8, 64), 256, 0, stream>>>(
        H0b, Wt3, b3, nullptr, nullptr, Y3, partial, 8192, 1024, 1720, 1728);
    k_bn_finalize<<<4, 256, 0, stream>>>(partial, g3, be3, a3, c3, 1024, 64, invB);

    k_gemm_mfma<true><<<dim3(4, 64), 256, 0, stream>>>(
        Y3, Wt4, b4, a3, c3, Y4, partial, 8192, 512, 1024, 1024);
    k_bn_finalize<<<2, 256, 0, stream>>>(partial, g4, be4, a4, c4, 512, 64, invB);

    k_gemm_mfma<true><<<dim3(2, 64), 256, 0, stream>>>(
        Y4, Wt5, b5, a4, c4, Y5, partial, 8192, 256, 512, 512);
    k_bn_finalize<<<1, 256, 0, stream>>>(partial, g5, be5, a5, c5, 256, 64, invB);

    k_tail<<<256, 256, 0, stream>>>(Y5, a5, c5, W6, b6, W7, b7, W8, b8, out);
}

// Round 3
// 366.434 us; speedup vs baseline: 2.4116x; 1.0786x over previous
//
#include <hip/hip_runtime.h>

// ---------------------------------------------------------------------------
// WinBinVecFC round 3: all-bf16 MFMA mid section with global_load_lds staging.
// BN affine folded into next layer's weights: BN(y)@W = y@(diag(a)W) + (c@W+b)
// -> every GEMM is a plain bf16 GEMM (m97 structure: 128x128 tile, BK=64,
//    global_load_lds dwordx4 staging, linear LDS, 2 barriers per K-step).
// Activations stored bf16. BN stats fp32 via deterministic per-blockrow
// partials. Tail (256->64->32->2) stays f32 vector.
// ---------------------------------------------------------------------------

typedef __attribute__((ext_vector_type(8))) short bfrag;    // 8 bf16
typedef __attribute__((ext_vector_type(4))) float f32x4v;   // MFMA C/D

__device__ __forceinline__ float4 ld4(const float* p) {
    return *reinterpret_cast<const float4*>(p);
}
__device__ __forceinline__ void st4(float* p, float4 v) {
    *reinterpret_cast<float4*>(p) = v;
}
__device__ __forceinline__ unsigned short f2b(float f) {   // RNE f32->bf16
    union { float f; unsigned u; } v; v.f = f;
    unsigned r = v.u + 0x7fffu + ((v.u >> 16) & 1u);
    return (unsigned short)(r >> 16);
}
__device__ __forceinline__ float b2f(unsigned short b) {
    union { unsigned u; float f; } v; v.u = (unsigned)b << 16;
    return v.f;
}
// async global->LDS, 16 B per lane (wave-uniform LDS base + lane*16)
__device__ __forceinline__ void async16(unsigned short* lds,
                                        const unsigned short* g) {
    __builtin_amdgcn_global_load_lds(
        (const __attribute__((address_space(1))) void*)g,
        (__attribute__((address_space(3))) void*)lds, 16, 0, 0);
}

// ---------------------------------------------------------------------------
// Kernel 0: H0[b][g*4+o] = bf16(sum_i X[b,g,i]*Wg[g,i,o] + bg[g,o]),
// row stride 1728 (cols 1720..1727 zeroed by the g==429 threads).
// ---------------------------------------------------------------------------
__global__ __launch_bounds__(256) void k_grouped(
    const float* __restrict__ X, const float* __restrict__ Wg,
    const float* __restrict__ bg, unsigned short* __restrict__ H0)
{
    __shared__ float Xs[6400];                 // 256 pairs * 25 floats
    const int tid = threadIdx.x;
    const size_t base = (size_t)blockIdx.x * 6400;
    #pragma unroll
    for (int c = 0; c < 25; ++c)
        Xs[c * 256 + tid] = X[base + c * 256 + tid];   // coalesced
    __syncthreads();

    const int idx = blockIdx.x * 256 + tid;    // b*430+g (exact cover)
    const int b = idx / 430;
    const int g = idx - b * 430;
    const float* __restrict__ w = Wg + g * 100;
    float4 acc = ld4(bg + g * 4);
    const float* x = &Xs[tid * 25];
    #pragma unroll
    for (int i = 0; i < 25; ++i) {
        const float xi = x[i];
        const float4 wv = ld4(w + i * 4);      // L2-resident (172 KB)
        acc.x = fmaf(xi, wv.x, acc.x);
        acc.y = fmaf(xi, wv.y, acc.y);
        acc.z = fmaf(xi, wv.z, acc.z);
        acc.w = fmaf(xi, wv.w, acc.w);
    }
    ushort4 o;
    o.x = f2b(acc.x); o.y = f2b(acc.y); o.z = f2b(acc.z); o.w = f2b(acc.w);
    unsigned short* row = H0 + (size_t)b * 1728;
    *reinterpret_cast<ushort4*>(row + g * 4) = o;
    if (g == 429) {                            // zero the K-pad
        const ushort4 z = {0, 0, 0, 0};
        *reinterpret_cast<ushort4*>(row + 1720) = z;
        *reinterpret_cast<ushort4*>(row + 1724) = z;
    }
}

// ---------------------------------------------------------------------------
// Wt[n][k] = bf16(W[k][n]), zero-pad k in [K, Kpad). block (32,8).
// ---------------------------------------------------------------------------
__global__ __launch_bounds__(256) void k_transpose_w(
    const float* __restrict__ W, unsigned short* __restrict__ Wt,
    int K, int N, int Kpad)
{
    __shared__ float t[32][33];
    const int tx = threadIdx.x, ty = threadIdx.y;
    const int k0 = blockIdx.y * 32, n0 = blockIdx.x * 32;
    #pragma unroll
    for (int r = 0; r < 4; ++r) {
        const int k = k0 + ty + r * 8;
        t[ty + r * 8][tx] = (k < K) ? W[(size_t)k * N + n0 + tx] : 0.f;
    }
    __syncthreads();
    #pragma unroll
    for (int r = 0; r < 4; ++r) {
        const int n = n0 + ty + r * 8;
        Wt[(size_t)n * Kpad + k0 + tx] = f2b(t[tx][ty + r * 8]);
    }
}

// ---------------------------------------------------------------------------
// Wt[n][k] = bf16(affa[k] * W[k][n]); bpart[by][n] = sum_{k in tile} affc[k]*W[k][n]
// (BN affine folded into weights + bias). block (32,8), grid (N/32, K/32).
// ---------------------------------------------------------------------------
__global__ __launch_bounds__(256) void k_scale_w(
    const float* __restrict__ W,
    const float* __restrict__ affa, const float* __restrict__ affc,
    unsigned short* __restrict__ Wt, float* __restrict__ bpart,
    int K, int N)
{
    __shared__ float t[32][33];
    __shared__ float red[8][33];
    const int tx = threadIdx.x, ty = threadIdx.y;
    const int k0 = blockIdx.y * 32, n0 = blockIdx.x * 32;
    #pragma unroll
    for (int r = 0; r < 4; ++r)
        t[ty + r * 8][tx] = W[(size_t)(k0 + ty + r * 8) * N + n0 + tx];
    __syncthreads();
    #pragma unroll
    for (int r = 0; r < 4; ++r) {
        const int n = n0 + ty + r * 8;
        Wt[(size_t)n * K + k0 + tx] = f2b(affa[k0 + tx] * t[tx][ty + r * 8]);
    }
    // bias fold partial: sum over this k-tile of affc[k]*W[k][n], n = n0+tx
    float s = 0.f;
    #pragma unroll
    for (int j = 0; j < 4; ++j) {
        const int kl = ty * 4 + j;
        s = fmaf(affc[k0 + kl], t[kl][tx], s);
    }
    red[ty][tx] = s;
    __syncthreads();
    if (ty == 0) {
        float acc = red[0][tx];
        #pragma unroll
        for (int r = 1; r < 8; ++r) acc += red[r][tx];
        bpart[(size_t)blockIdx.y * N + n0 + tx] = acc;
    }
}

// ---------------------------------------------------------------------------
// Plain bf16 MFMA GEMM (m97 structure): Y = A @ Bt^T + bias(+Σbpart),
// Y stored bf16, fused f32 column sum/sumsq partials for BN.
// A [M][Ka] bf16, Bt [N][Ka] bf16, Ka % 64 == 0 (pads zeroed).
// BM=BN=128, BK=64, 256 thr = 4 waves (2x2), wave tile 64x64 (4x4 frags).
// Staging via global_load_lds dwordx4 into linear LDS [128][64].
// ---------------------------------------------------------------------------
template<bool BPART>
__global__ __launch_bounds__(256) void k_gemm(
    const unsigned short* __restrict__ A,
    const unsigned short* __restrict__ Bt,
    const float* __restrict__ bias,
    const float* __restrict__ bpart, int nbp,
    unsigned short* __restrict__ Y, float* __restrict__ partial,
    int M, int N, int Ka)
{
    __shared__ __align__(16) unsigned short As[128 * 64];   // 16 KB
    __shared__ __align__(16) unsigned short Bs[128 * 64];   // 16 KB

    const int tid = threadIdx.x;
    const int m0 = blockIdx.y * 128, n0 = blockIdx.x * 128;
    const int lane = tid & 63, wid = tid >> 6;
    const int wm = wid >> 1, wn = wid & 1;     // 2x2 wave grid
    const int lr = lane & 15, hi = lane >> 4;

    // staging: wave wid covers tile rows [wid*32, wid*32+32), 4 calls x 8 rows
    const int srow = wid * 32 + (lane >> 3);
    const int scol = (lane & 7) * 8;
    const unsigned short* Ap = A + (size_t)(m0 + srow) * Ka + scol;
    const unsigned short* Bp = Bt + (size_t)(n0 + srow) * Ka + scol;
    unsigned short* Asd = &As[(wid * 32) * 64];   // wave-uniform dests
    unsigned short* Bsd = &Bs[(wid * 32) * 64];

    f32x4v acc[4][4] = {};

    const int Ksteps = Ka >> 6;
    #pragma unroll
    for (int c = 0; c < 4; ++c) {
        async16(Asd + c * 8 * 64, Ap + (size_t)(c * 8) * Ka);
        async16(Bsd + c * 8 * 64, Bp + (size_t)(c * 8) * Ka);
    }

    for (int s = 0; s < Ksteps; ++s) {
        __syncthreads();                       // drains vmcnt -> LDS ready
        #pragma unroll
        for (int kc = 0; kc < 64; kc += 32) {
            bfrag af[4], bf[4];
            #pragma unroll
            for (int mt = 0; mt < 4; ++mt)
                af[mt] = *reinterpret_cast<const bfrag*>(
                    &As[(wm * 64 + mt * 16 + lr) * 64 + kc + hi * 8]);
            #pragma unroll
            for (int nt = 0; nt < 4; ++nt)
                bf[nt] = *reinterpret_cast<const bfrag*>(
                    &Bs[(wn * 64 + nt * 16 + lr) * 64 + kc + hi * 8]);
            #pragma unroll
            for (int mt = 0; mt < 4; ++mt)
                #pragma unroll
                for (int nt = 0; nt < 4; ++nt)
                    acc[mt][nt] = __builtin_amdgcn_mfma_f32_16x16x32_bf16(
                        af[mt], bf[nt], acc[mt][nt], 0, 0, 0);
        }
        __syncthreads();                       // all waves done reading LDS
        if (s + 1 < Ksteps) {
            const int k0 = (s + 1) << 6;
            #pragma unroll
            for (int c = 0; c < 4; ++c) {
                async16(Asd + c * 8 * 64, Ap + (size_t)(c * 8) * Ka + k0);
                async16(Bsd + c * 8 * 64, Bp + (size_t)(c * 8) * Ka + k0);
            }
        }
    }

    // --- epilogue: bias (+ folded c@W partials), bf16 store, column stats ---
    float bcol[4];
    #pragma unroll
    for (int nt = 0; nt < 4; ++nt) {
        const int n = n0 + wn * 64 + nt * 16 + lr;
        float b = bias[n];
        if (BPART)
            for (int t = 0; t < nbp; ++t) b += bpart[(size_t)t * N + n];
        bcol[nt] = b;
    }

    float csum[4] = {0.f, 0.f, 0.f, 0.f}, csq[4] = {0.f, 0.f, 0.f, 0.f};
    #pragma unroll
    for (int mt = 0; mt < 4; ++mt)
        #pragma unroll
        for (int e = 0; e < 4; ++e) {
            const int m = m0 + wm * 64 + mt * 16 + hi * 4 + e;
            #pragma unroll
            for (int nt = 0; nt < 4; ++nt) {
                const float v = acc[mt][nt][e] + bcol[nt];
                Y[(size_t)m * N + n0 + wn * 64 + nt * 16 + lr] = f2b(v);
                csum[nt] += v; csq[nt] += v * v;
            }
        }

    // deterministic block-level column reduction (reuse LDS as f32)
    __syncthreads();
    float* redS = (float*)As;                  // 8 slots x 128 cols
    float* redQ = (float*)Bs;
    const int slot = wm * 4 + hi;
    #pragma unroll
    for (int nt = 0; nt < 4; ++nt) {
        const int c = wn * 64 + nt * 16 + lr;
        redS[slot * 128 + c] = csum[nt];
        redQ[slot * 128 + c] = csq[nt];
    }
    __syncthreads();
    if (tid < 128) {
        float s = 0.f, q = 0.f;
        #pragma unroll
        for (int t = 0; t < 8; ++t) {
            s += redS[t * 128 + tid];
            q += redQ[t * 128 + tid];
        }
        partial[(size_t)blockIdx.y * (2 * N) + n0 + tid] = s;
        partial[(size_t)blockIdx.y * (2 * N) + N + n0 + tid] = q;
    }
}

// ---------------------------------------------------------------------------
// BN finalize: a = gamma*rsqrt(var+eps), c = beta - mean*a
// ---------------------------------------------------------------------------
__global__ __launch_bounds__(256) void k_bn_finalize(
    const float* __restrict__ partial,
    const float* __restrict__ gamma, const float* __restrict__ beta,
    float* __restrict__ affa, float* __restrict__ affc,
    int N, int Mtiles, float invB)
{
    const int c = blockIdx.x * 256 + threadIdx.x;
    if (c >= N) return;
    float S = 0.f, Q = 0.f;
    for (int t = 0; t < Mtiles; ++t) {
        S += partial[(size_t)t * 2 * N + c];
        Q += partial[(size_t)t * 2 * N + N + c];
    }
    const float mean = S * invB;
    const float var = fmaxf(Q * invB - mean * mean, 0.f);
    const float s = rsqrtf(var + 1e-5f);
    const float a = gamma[c] * s;
    affa[c] = a;
    affc[c] = beta[c] - mean * a;
}

// ---------------------------------------------------------------------------
// Tail: out = ((BN5(Y5) @ W6 + b6) @ W7 + b7) @ W8 + b8   (256->64->32->2)
// Y5 is bf16; BN5 affine (a5,c5) applied in f32 during load.
// ---------------------------------------------------------------------------
__global__ __launch_bounds__(256) void k_tail(
    const unsigned short* __restrict__ Y5,
    const float* __restrict__ a5, const float* __restrict__ c5,
    const float* __restrict__ W6, const float* __restrict__ b6,
    const float* __restrict__ W7, const float* __restrict__ b7,
    const float* __restrict__ W8, const float* __restrict__ b8,
    float* __restrict__ out)
{
    __shared__ float Xs[32][260];
    __shared__ float h6s[32][66];
    __shared__ float h7s[32][34];
    const int tid = threadIdx.x;
    const int row0 = blockIdx.x * 32;

    // phase A: 32x256 bf16 tile -> f32 with BN affine
    #pragma unroll
    for (int c = 0; c < 4; ++c) {
        const int id = c * 256 + tid;          // 0..1023, 8 bf16 each
        const int r = id >> 5;
        const int k = (id & 31) * 8;
        const ushort4 u0 = *reinterpret_cast<const ushort4*>(
            Y5 + (size_t)(row0 + r) * 256 + k);
        const ushort4 u1 = *reinterpret_cast<const ushort4*>(
            Y5 + (size_t)(row0 + r) * 256 + k + 4);
        const float4 aa0 = ld4(a5 + k),     cc0 = ld4(c5 + k);
        const float4 aa1 = ld4(a5 + k + 4), cc1 = ld4(c5 + k + 4);
        Xs[r][k + 0] = fmaf(b2f(u0.x), aa0.x, cc0.x);
        Xs[r][k + 1] = fmaf(b2f(u0.y), aa0.y, cc0.y);
        Xs[r][k + 2] = fmaf(b2f(u0.z), aa0.z, cc0.z);
        Xs[r][k + 3] = fmaf(b2f(u0.w), aa0.w, cc0.w);
        Xs[r][k + 4] = fmaf(b2f(u1.x), aa1.x, cc1.x);
        Xs[r][k + 5] = fmaf(b2f(u1.y), aa1.y, cc1.y);
        Xs[r][k + 6] = fmaf(b2f(u1.z), aa1.z, cc1.z);
        Xs[r][k + 7] = fmaf(b2f(u1.w), aa1.w, cc1.w);
    }
    __syncthreads();

    {   // h6[32][64]
        const int o = tid & 63;
        const int rg = tid >> 6;
        const float bb = b6[o];
        float acc[8];
        #pragma unroll
        for (int i = 0; i < 8; ++i) acc[i] = bb;
        for (int k = 0; k < 256; ++k) {
            const float w = W6[k * 64 + o];
            #pragma unroll
            for (int i = 0; i < 8; ++i)
                acc[i] = fmaf(Xs[rg * 8 + i][k], w, acc[i]);
        }
        #pragma unroll
        for (int i = 0; i < 8; ++i) h6s[rg * 8 + i][o] = acc[i];
    }
    __syncthreads();

    {   // h7[32][32]
        const int o = tid & 31;
        const int rg = tid >> 5;
        const float bb = b7[o];
        float acc[4];
        #pragma unroll
        for (int i = 0; i < 4; ++i) acc[i] = bb;
        for (int k = 0; k < 64; ++k) {
            const float w = W7[k * 32 + o];
            #pragma unroll
            for (int i = 0; i < 4; ++i)
                acc[i] = fmaf(h6s[rg * 4 + i][k], w, acc[i]);
        }
        #pragma unroll
        for (int i = 0; i < 4; ++i) h7s[rg * 4 + i][o] = acc[i];
    }
    __syncthreads();

    if (tid < 64) {
        const int r = tid >> 1, o = tid & 1;
        float acc = b8[o];
        #pragma unroll
        for (int k = 0; k < 32; ++k)
            acc = fmaf(h7s[r][k], W8[k * 2 + o], acc);
        out[(size_t)(row0 + r) * 2 + o] = acc;
    }
}

// ---------------------------------------------------------------------------
extern "C" void kernel_launch(void* const* d_in, const int* in_sizes, int n_in,
                              void* d_out, int out_size, void* d_ws, size_t ws_size,
                              hipStream_t stream)
{
    const float* X   = (const float*)d_in[0];
    const float* Wg  = (const float*)d_in[1];
    const float* bg  = (const float*)d_in[2];
    const float* W3  = (const float*)d_in[3];
    const float* b3  = (const float*)d_in[4];
    const float* g3  = (const float*)d_in[5];
    const float* be3 = (const float*)d_in[6];
    const float* W4  = (const float*)d_in[7];
    const float* b4  = (const float*)d_in[8];
    const float* g4  = (const float*)d_in[9];
    const float* be4 = (const float*)d_in[10];
    const float* W5  = (const float*)d_in[11];
    const float* b5  = (const float*)d_in[12];
    const float* g5  = (const float*)d_in[13];
    const float* be5 = (const float*)d_in[14];
    const float* W6  = (const float*)d_in[15];
    const float* b6  = (const float*)d_in[16];
    const float* W7  = (const float*)d_in[17];
    const float* b7  = (const float*)d_in[18];
    const float* W8  = (const float*)d_in[19];
    const float* b8  = (const float*)d_in[20];
    float* out = (float*)d_out;

    // workspace layout (bytes, all 256-aligned):
    char* wsb = (char*)d_ws;
    unsigned short* H0  = (unsigned short*)wsb;                  // [8192][1728] bf16 (28,311,552)
    unsigned short* Y4  = (unsigned short*)wsb;                  // alias (H0 dead)
    unsigned short* Y3  = (unsigned short*)(wsb + 28311552);     // [8192][1024] bf16 (16,777,216)
    unsigned short* Y5  = Y3;                                    // alias (Y3 dead)
    unsigned short* Wt3 = (unsigned short*)(wsb + 45088768);     // [1024][1728] bf16
    unsigned short* Wt4 = (unsigned short*)(wsb + 48627712);     // [512][1024] bf16
    unsigned short* Wt5 = (unsigned short*)(wsb + 49676288);     // [256][512]  bf16
    float* partial      = (float*)(wsb + 49938432);              // [64][2*1024]
    float* bpart4       = (float*)(wsb + 50462720);              // [32][512]
    float* bpart5       = (float*)(wsb + 50528256);              // [16][256]
    float* a3 = (float*)(wsb + 50544640);
    float* c3 = a3 + 1024;
    float* a4 = c3 + 1024;
    float* c4 = a4 + 512;
    float* a5 = c4 + 512;
    float* c5 = a5 + 256;

    const float invB = 1.f / 8192.f;

    k_transpose_w<<<dim3(32, 54), dim3(32, 8), 0, stream>>>(W3, Wt3, 1720, 1024, 1728);
    k_grouped<<<13760, 256, 0, stream>>>(X, Wg, bg, H0);

    k_gemm<false><<<dim3(8, 64), 256, 0, stream>>>(
        H0, Wt3, b3, nullptr, 0, Y3, partial, 8192, 1024, 1728);
    k_bn_finalize<<<4, 256, 0, stream>>>(partial, g3, be3, a3, c3, 1024, 64, invB);

    k_scale_w<<<dim3(16, 32), dim3(32, 8), 0, stream>>>(W4, a3, c3, Wt4, bpart4, 1024, 512);
    k_gemm<true><<<dim3(4, 64), 256, 0, stream>>>(
        Y3, Wt4, b4, bpart4, 32, Y4, partial, 8192, 512, 1024);
    k_bn_finalize<<<2, 256, 0, stream>>>(partial, g4, be4, a4, c4, 512, 64, invB);

    k_scale_w<<<dim3(8, 16), dim3(32, 8), 0, stream>>>(W5, a4, c4, Wt5, bpart5, 512, 256);
    k_gemm<true><<<dim3(2, 64), 256, 0, stream>>>(
        Y4, Wt5, b5, bpart5, 16, Y5, partial, 8192, 256, 512);
    k_bn_finalize<<<1, 256, 0, stream>>>(partial, g5, be5, a5, c5, 256, 64, invB);

    k_tail<<<256, 256, 0, stream>>>(Y5, a5, c5, W6, b6, W7, b7, W8, b8, out);
}

// Round 4
// 296.996 us; speedup vs baseline: 2.9755x; 1.2338x over previous
//
#include <hip/hip_runtime.h>

// ---------------------------------------------------------------------------
// WinBinVecFC round 4: fix k_grouped's transaction-bound Wg access.
// Block = 32 b-rows x 8 g-cols; Wg(8g)=3.2KB + X tile staged in LDS; W reads
// become LDS broadcasts instead of 64-line-divergent global float4 loads.
// Everything else identical to round 3 (bf16 MFMA GEMMs w/ global_load_lds,
// BN folded into weights, bf16 activations, f32 tail).
// ---------------------------------------------------------------------------

typedef __attribute__((ext_vector_type(8))) short bfrag;    // 8 bf16
typedef __attribute__((ext_vector_type(4))) float f32x4v;   // MFMA C/D

__device__ __forceinline__ float4 ld4(const float* p) {
    return *reinterpret_cast<const float4*>(p);
}
__device__ __forceinline__ void st4(float* p, float4 v) {
    *reinterpret_cast<float4*>(p) = v;
}
__device__ __forceinline__ unsigned short f2b(float f) {   // RNE f32->bf16
    union { float f; unsigned u; } v; v.f = f;
    unsigned r = v.u + 0x7fffu + ((v.u >> 16) & 1u);
    return (unsigned short)(r >> 16);
}
__device__ __forceinline__ float b2f(unsigned short b) {
    union { unsigned u; float f; } v; v.u = (unsigned)b << 16;
    return v.f;
}
// async global->LDS, 16 B per lane (wave-uniform LDS base + lane*16)
__device__ __forceinline__ void async16(unsigned short* lds,
                                        const unsigned short* g) {
    __builtin_amdgcn_global_load_lds(
        (const __attribute__((address_space(1))) void*)g,
        (__attribute__((address_space(3))) void*)lds, 16, 0, 0);
}

// ---------------------------------------------------------------------------
// Kernel 0 (restructured): block = 32 b x 8 g. H0 row stride 1728, pad zeroed.
// ---------------------------------------------------------------------------
__global__ __launch_bounds__(256) void k_grouped(
    const float* __restrict__ X, const float* __restrict__ Wg,
    const float* __restrict__ bg, unsigned short* __restrict__ H0)
{
    __shared__ float Xs[32 * 200];             // 25.6 KB
    __shared__ float Ws[800];                  // 3.2 KB (8 g x 100)
    __shared__ float Bs[32];                   // 8 g x 4 bias
    const int tid = threadIdx.x;
    const int b0 = blockIdx.x * 32;
    const int g0 = blockIdx.y * 8;
    const int ng = (g0 + 8 <= 430) ? 8 : (430 - g0);   // 8 or 6

    // stage W (contiguous, coalesced) and bias
    for (int i = tid; i < ng * 100; i += 256)
        Ws[i] = Wg[g0 * 100 + i];
    if (tid < ng * 4) Bs[tid] = bg[g0 * 4 + tid];

    // stage X tile: rows b0..b0+31, cols [g0*25, g0*25 + ng*25)
    if (ng == 8) {
        #pragma unroll
        for (int t = 0; t < 25; ++t) {
            const int i = t * 256 + tid;       // 0..6399
            const int r = i / 200;             // const divisor -> magic mul
            const int c = i - r * 200;
            Xs[r * 200 + c] = X[(size_t)(b0 + r) * 10750 + g0 * 25 + c];
        }
    } else {
        for (int i = tid; i < 32 * 150; i += 256) {
            const int r = i / 150;
            const int c = i - r * 150;
            Xs[r * 200 + c] = X[(size_t)(b0 + r) * 10750 + g0 * 25 + c];
        }
    }
    __syncthreads();

    // compute: thread (bl, gl) -> one (b, g) output of 4
    const int bl = tid >> 3, gl = tid & 7;
    if (gl < ng) {
        const float* __restrict__ w = &Ws[gl * 100];
        const float* __restrict__ x = &Xs[bl * 200 + gl * 25];
        float4 acc = ld4(&Bs[gl * 4]);
        #pragma unroll
        for (int i = 0; i < 25; ++i) {
            const float xi = x[i];
            const float4 wv = ld4(&w[i * 4]);  // 8-way broadcast, no conflicts
            acc.x = fmaf(xi, wv.x, acc.x);
            acc.y = fmaf(xi, wv.y, acc.y);
            acc.z = fmaf(xi, wv.z, acc.z);
            acc.w = fmaf(xi, wv.w, acc.w);
        }
        ushort4 o;
        o.x = f2b(acc.x); o.y = f2b(acc.y); o.z = f2b(acc.z); o.w = f2b(acc.w);
        *reinterpret_cast<ushort4*>(
            H0 + (size_t)(b0 + bl) * 1728 + (size_t)(g0 + gl) * 4) = o;
    }
    // zero the K-pad (cols 1720..1727) once per row, via the last g-tile
    if (blockIdx.y == 53) {
        const int r = tid >> 3, c = tid & 7;
        H0[(size_t)(b0 + r) * 1728 + 1720 + c] = 0;
    }
}

// ---------------------------------------------------------------------------
// Wt[n][k] = bf16(W[k][n]), zero-pad k in [K, Kpad). block (32,8).
// ---------------------------------------------------------------------------
__global__ __launch_bounds__(256) void k_transpose_w(
    const float* __restrict__ W, unsigned short* __restrict__ Wt,
    int K, int N, int Kpad)
{
    __shared__ float t[32][33];
    const int tx = threadIdx.x, ty = threadIdx.y;
    const int k0 = blockIdx.y * 32, n0 = blockIdx.x * 32;
    #pragma unroll
    for (int r = 0; r < 4; ++r) {
        const int k = k0 + ty + r * 8;
        t[ty + r * 8][tx] = (k < K) ? W[(size_t)k * N + n0 + tx] : 0.f;
    }
    __syncthreads();
    #pragma unroll
    for (int r = 0; r < 4; ++r) {
        const int n = n0 + ty + r * 8;
        Wt[(size_t)n * Kpad + k0 + tx] = f2b(t[tx][ty + r * 8]);
    }
}

// ---------------------------------------------------------------------------
// Wt[n][k] = bf16(affa[k]*W[k][n]); bpart[by][n] = sum_k affc[k]*W[k][n]
// ---------------------------------------------------------------------------
__global__ __launch_bounds__(256) void k_scale_w(
    const float* __restrict__ W,
    const float* __restrict__ affa, const float* __restrict__ affc,
    unsigned short* __restrict__ Wt, float* __restrict__ bpart,
    int K, int N)
{
    __shared__ float t[32][33];
    __shared__ float red[8][33];
    const int tx = threadIdx.x, ty = threadIdx.y;
    const int k0 = blockIdx.y * 32, n0 = blockIdx.x * 32;
    #pragma unroll
    for (int r = 0; r < 4; ++r)
        t[ty + r * 8][tx] = W[(size_t)(k0 + ty + r * 8) * N + n0 + tx];
    __syncthreads();
    #pragma unroll
    for (int r = 0; r < 4; ++r) {
        const int n = n0 + ty + r * 8;
        Wt[(size_t)n * K + k0 + tx] = f2b(affa[k0 + tx] * t[tx][ty + r * 8]);
    }
    float s = 0.f;
    #pragma unroll
    for (int j = 0; j < 4; ++j) {
        const int kl = ty * 4 + j;
        s = fmaf(affc[k0 + kl], t[kl][tx], s);
    }
    red[ty][tx] = s;
    __syncthreads();
    if (ty == 0) {
        float acc = red[0][tx];
        #pragma unroll
        for (int r = 1; r < 8; ++r) acc += red[r][tx];
        bpart[(size_t)blockIdx.y * N + n0 + tx] = acc;
    }
}

// ---------------------------------------------------------------------------
// Plain bf16 MFMA GEMM (m97 structure): Y = A @ Bt^T + bias(+Σbpart),
// Y stored bf16, fused f32 column sum/sumsq partials for BN.
// ---------------------------------------------------------------------------
template<bool BPART>
__global__ __launch_bounds__(256) void k_gemm(
    const unsigned short* __restrict__ A,
    const unsigned short* __restrict__ Bt,
    const float* __restrict__ bias,
    const float* __restrict__ bpart, int nbp,
    unsigned short* __restrict__ Y, float* __restrict__ partial,
    int M, int N, int Ka)
{
    __shared__ __align__(16) unsigned short As[128 * 64];   // 16 KB
    __shared__ __align__(16) unsigned short Bs[128 * 64];   // 16 KB

    const int tid = threadIdx.x;
    const int m0 = blockIdx.y * 128, n0 = blockIdx.x * 128;
    const int lane = tid & 63, wid = tid >> 6;
    const int wm = wid >> 1, wn = wid & 1;     // 2x2 wave grid
    const int lr = lane & 15, hi = lane >> 4;

    const int srow = wid * 32 + (lane >> 3);
    const int scol = (lane & 7) * 8;
    const unsigned short* Ap = A + (size_t)(m0 + srow) * Ka + scol;
    const unsigned short* Bp = Bt + (size_t)(n0 + srow) * Ka + scol;
    unsigned short* Asd = &As[(wid * 32) * 64];
    unsigned short* Bsd = &Bs[(wid * 32) * 64];

    f32x4v acc[4][4] = {};

    const int Ksteps = Ka >> 6;
    #pragma unroll
    for (int c = 0; c < 4; ++c) {
        async16(Asd + c * 8 * 64, Ap + (size_t)(c * 8) * Ka);
        async16(Bsd + c * 8 * 64, Bp + (size_t)(c * 8) * Ka);
    }

    for (int s = 0; s < Ksteps; ++s) {
        __syncthreads();
        #pragma unroll
        for (int kc = 0; kc < 64; kc += 32) {
            bfrag af[4], bf[4];
            #pragma unroll
            for (int mt = 0; mt < 4; ++mt)
                af[mt] = *reinterpret_cast<const bfrag*>(
                    &As[(wm * 64 + mt * 16 + lr) * 64 + kc + hi * 8]);
            #pragma unroll
            for (int nt = 0; nt < 4; ++nt)
                bf[nt] = *reinterpret_cast<const bfrag*>(
                    &Bs[(wn * 64 + nt * 16 + lr) * 64 + kc + hi * 8]);
            #pragma unroll
            for (int mt = 0; mt < 4; ++mt)
                #pragma unroll
                for (int nt = 0; nt < 4; ++nt)
                    acc[mt][nt] = __builtin_amdgcn_mfma_f32_16x16x32_bf16(
                        af[mt], bf[nt], acc[mt][nt], 0, 0, 0);
        }
        __syncthreads();
        if (s + 1 < Ksteps) {
            const int k0 = (s + 1) << 6;
            #pragma unroll
            for (int c = 0; c < 4; ++c) {
                async16(Asd + c * 8 * 64, Ap + (size_t)(c * 8) * Ka + k0);
                async16(Bsd + c * 8 * 64, Bp + (size_t)(c * 8) * Ka + k0);
            }
        }
    }

    float bcol[4];
    #pragma unroll
    for (int nt = 0; nt < 4; ++nt) {
        const int n = n0 + wn * 64 + nt * 16 + lr;
        float b = bias[n];
        if (BPART)
            for (int t = 0; t < nbp; ++t) b += bpart[(size_t)t * N + n];
        bcol[nt] = b;
    }

    float csum[4] = {0.f, 0.f, 0.f, 0.f}, csq[4] = {0.f, 0.f, 0.f, 0.f};
    #pragma unroll
    for (int mt = 0; mt < 4; ++mt)
        #pragma unroll
        for (int e = 0; e < 4; ++e) {
            const int m = m0 + wm * 64 + mt * 16 + hi * 4 + e;
            #pragma unroll
            for (int nt = 0; nt < 4; ++nt) {
                const float v = acc[mt][nt][e] + bcol[nt];
                Y[(size_t)m * N + n0 + wn * 64 + nt * 16 + lr] = f2b(v);
                csum[nt] += v; csq[nt] += v * v;
            }
        }

    __syncthreads();
    float* redS = (float*)As;
    float* redQ = (float*)Bs;
    const int slot = wm * 4 + hi;
    #pragma unroll
    for (int nt = 0; nt < 4; ++nt) {
        const int c = wn * 64 + nt * 16 + lr;
        redS[slot * 128 + c] = csum[nt];
        redQ[slot * 128 + c] = csq[nt];
    }
    __syncthreads();
    if (tid < 128) {
        float s = 0.f, q = 0.f;
        #pragma unroll
        for (int t = 0; t < 8; ++t) {
            s += redS[t * 128 + tid];
            q += redQ[t * 128 + tid];
        }
        partial[(size_t)blockIdx.y * (2 * N) + n0 + tid] = s;
        partial[(size_t)blockIdx.y * (2 * N) + N + n0 + tid] = q;
    }
}

// ---------------------------------------------------------------------------
__global__ __launch_bounds__(256) void k_bn_finalize(
    const float* __restrict__ partial,
    const float* __restrict__ gamma, const float* __restrict__ beta,
    float* __restrict__ affa, float* __restrict__ affc,
    int N, int Mtiles, float invB)
{
    const int c = blockIdx.x * 256 + threadIdx.x;
    if (c >= N) return;
    float S = 0.f, Q = 0.f;
    for (int t = 0; t < Mtiles; ++t) {
        S += partial[(size_t)t * 2 * N + c];
        Q += partial[(size_t)t * 2 * N + N + c];
    }
    const float mean = S * invB;
    const float var = fmaxf(Q * invB - mean * mean, 0.f);
    const float s = rsqrtf(var + 1e-5f);
    const float a = gamma[c] * s;
    affa[c] = a;
    affc[c] = beta[c] - mean * a;
}

// ---------------------------------------------------------------------------
// Tail: out = ((BN5(Y5) @ W6 + b6) @ W7 + b7) @ W8 + b8   (256->64->32->2)
// ---------------------------------------------------------------------------
__global__ __launch_bounds__(256) void k_tail(
    const unsigned short* __restrict__ Y5,
    const float* __restrict__ a5, const float* __restrict__ c5,
    const float* __restrict__ W6, const float* __restrict__ b6,
    const float* __restrict__ W7, const float* __restrict__ b7,
    const float* __restrict__ W8, const float* __restrict__ b8,
    float* __restrict__ out)
{
    __shared__ float Xs[32][260];
    __shared__ float h6s[32][66];
    __shared__ float h7s[32][34];
    const int tid = threadIdx.x;
    const int row0 = blockIdx.x * 32;

    #pragma unroll
    for (int c = 0; c < 4; ++c) {
        const int id = c * 256 + tid;
        const int r = id >> 5;
        const int k = (id & 31) * 8;
        const ushort4 u0 = *reinterpret_cast<const ushort4*>(
            Y5 + (size_t)(row0 + r) * 256 + k);
        const ushort4 u1 = *reinterpret_cast<const ushort4*>(
            Y5 + (size_t)(row0 + r) * 256 + k + 4);
        const float4 aa0 = ld4(a5 + k),     cc0 = ld4(c5 + k);
        const float4 aa1 = ld4(a5 + k + 4), cc1 = ld4(c5 + k + 4);
        Xs[r][k + 0] = fmaf(b2f(u0.x), aa0.x, cc0.x);
        Xs[r][k + 1] = fmaf(b2f(u0.y), aa0.y, cc0.y);
        Xs[r][k + 2] = fmaf(b2f(u0.z), aa0.z, cc0.z);
        Xs[r][k + 3] = fmaf(b2f(u0.w), aa0.w, cc0.w);
        Xs[r][k + 4] = fmaf(b2f(u1.x), aa1.x, cc1.x);
        Xs[r][k + 5] = fmaf(b2f(u1.y), aa1.y, cc1.y);
        Xs[r][k + 6] = fmaf(b2f(u1.z), aa1.z, cc1.z);
        Xs[r][k + 7] = fmaf(b2f(u1.w), aa1.w, cc1.w);
    }
    __syncthreads();

    {   // h6[32][64]
        const int o = tid & 63;
        const int rg = tid >> 6;
        const float bb = b6[o];
        float acc[8];
        #pragma unroll
        for (int i = 0; i < 8; ++i) acc[i] = bb;
        for (int k = 0; k < 256; ++k) {
            const float w = W6[k * 64 + o];
            #pragma unroll
            for (int i = 0; i < 8; ++i)
                acc[i] = fmaf(Xs[rg * 8 + i][k], w, acc[i]);
        }
        #pragma unroll
        for (int i = 0; i < 8; ++i) h6s[rg * 8 + i][o] = acc[i];
    }
    __syncthreads();

    {   // h7[32][32]
        const int o = tid & 31;
        const int rg = tid >> 5;
        const float bb = b7[o];
        float acc[4];
        #pragma unroll
        for (int i = 0; i < 4; ++i) acc[i] = bb;
        for (int k = 0; k < 64; ++k) {
            const float w = W7[k * 32 + o];
            #pragma unroll
            for (int i = 0; i < 4; ++i)
                acc[i] = fmaf(h6s[rg * 4 + i][k], w, acc[i]);
        }
        #pragma unroll
        for (int i = 0; i < 4; ++i) h7s[rg * 4 + i][o] = acc[i];
    }
    __syncthreads();

    if (tid < 64) {
        const int r = tid >> 1, o = tid & 1;
        float acc = b8[o];
        #pragma unroll
        for (int k = 0; k < 32; ++k)
            acc = fmaf(h7s[r][k], W8[k * 2 + o], acc);
        out[(size_t)(row0 + r) * 2 + o] = acc;
    }
}

// ---------------------------------------------------------------------------
extern "C" void kernel_launch(void* const* d_in, const int* in_sizes, int n_in,
                              void* d_out, int out_size, void* d_ws, size_t ws_size,
                              hipStream_t stream)
{
    const float* X   = (const float*)d_in[0];
    const float* Wg  = (const float*)d_in[1];
    const float* bg  = (const float*)d_in[2];
    const float* W3  = (const float*)d_in[3];
    const float* b3  = (const float*)d_in[4];
    const float* g3  = (const float*)d_in[5];
    const float* be3 = (const float*)d_in[6];
    const float* W4  = (const float*)d_in[7];
    const float* b4  = (const float*)d_in[8];
    const float* g4  = (const float*)d_in[9];
    const float* be4 = (const float*)d_in[10];
    const float* W5  = (const float*)d_in[11];
    const float* b5  = (const float*)d_in[12];
    const float* g5  = (const float*)d_in[13];
    const float* be5 = (const float*)d_in[14];
    const float* W6  = (const float*)d_in[15];
    const float* b6  = (const float*)d_in[16];
    const float* W7  = (const float*)d_in[17];
    const float* b7  = (const float*)d_in[18];
    const float* W8  = (const float*)d_in[19];
    const float* b8  = (const float*)d_in[20];
    float* out = (float*)d_out;

    char* wsb = (char*)d_ws;
    unsigned short* H0  = (unsigned short*)wsb;                  // [8192][1728] bf16
    unsigned short* Y4  = (unsigned short*)wsb;                  // alias (H0 dead)
    unsigned short* Y3  = (unsigned short*)(wsb + 28311552);     // [8192][1024] bf16
    unsigned short* Y5  = Y3;                                    // alias (Y3 dead)
    unsigned short* Wt3 = (unsigned short*)(wsb + 45088768);     // [1024][1728] bf16
    unsigned short* Wt4 = (unsigned short*)(wsb + 48627712);     // [512][1024] bf16
    unsigned short* Wt5 = (unsigned short*)(wsb + 49676288);     // [256][512]  bf16
    float* partial      = (float*)(wsb + 49938432);              // [64][2*1024]
    float* bpart4       = (float*)(wsb + 50462720);              // [32][512]
    float* bpart5       = (float*)(wsb + 50528256);              // [16][256]
    float* a3 = (float*)(wsb + 50544640);
    float* c3 = a3 + 1024;
    float* a4 = c3 + 1024;
    float* c4 = a4 + 512;
    float* a5 = c4 + 512;
    float* c5 = a5 + 256;

    const float invB = 1.f / 8192.f;

    k_transpose_w<<<dim3(32, 54), dim3(32, 8), 0, stream>>>(W3, Wt3, 1720, 1024, 1728);
    k_grouped<<<dim3(256, 54), 256, 0, stream>>>(X, Wg, bg, H0);

    k_gemm<false><<<dim3(8, 64), 256, 0, stream>>>(
        H0, Wt3, b3, nullptr, 0, Y3, partial, 8192, 1024, 1728);
    k_bn_finalize<<<4, 256, 0, stream>>>(partial, g3, be3, a3, c3, 1024, 64, invB);

    k_scale_w<<<dim3(16, 32), dim3(32, 8), 0, stream>>>(W4, a3, c3, Wt4, bpart4, 1024, 512);
    k_gemm<true><<<dim3(4, 64), 256, 0, stream>>>(
        Y3, Wt4, b4, bpart4, 32, Y4, partial, 8192, 512, 1024);
    k_bn_finalize<<<2, 256, 0, stream>>>(partial, g4, be4, a4, c4, 512, 64, invB);

    k_scale_w<<<dim3(8, 16), dim3(32, 8), 0, stream>>>(W5, a4, c4, Wt5, bpart5, 512, 256);
    k_gemm<true><<<dim3(2, 64), 256, 0, stream>>>(
        Y4, Wt5, b5, bpart5, 16, Y5, partial, 8192, 256, 512);
    k_bn_finalize<<<1, 256, 0, stream>>>(partial, g5, be5, a5, c5, 256, 64, invB);

    k_tail<<<256, 256, 0, stream>>>(Y5, a5, c5, W6, b6, W7, b7, W8, b8, out);
}